// Round 20
// baseline (843.830 us; speedup 1.0000x reference)
//
#include <hip/hip_runtime.h>
#include <math.h>

// HybridSNN: time-collapsed spiking CNN (exact fp32 replication, bit-exact orders).
//  kF: conv0+BN+ReLU+maxpool (h tile in LDS) + conv1 + serial LIF1 -> m1.
//      JT=64, unroll-1 pin, w1->LDS wl, w2 repack tail. (R18 frozen, ~45us)
//      + zeroes cnt_g/done_g (visible to kD via kernel-boundary coherence).
//  kD: maxpool(OR) + conv2 over bits + LIF2, FUSED with kE:
//      per-block 4-j partial popcounts -> device-scope atomicAdd into
//      cnt_g[b][t][oc] (order-independent integer sums -> bit-exact);
//      last-of-33 block per b (atomic done counter + threadfence) runs the
//      head: mean=cnt/129 -> fc1 -> LIF3 -> fc2 -> out. s2 buffer + kE kernel
//      ELIMINATED (8.6MB traffic + 1 launch boundary). Guideline-16-safe:
//      all cross-block data flows through device-scope atomics only.

#define NB 256
#define LX 4097
#define LQ 2049
#define LP 1025
#define LJ1 513
#define LP1 257
#define LJ2 129

#define M1S 520
#define JT 64     // kF j-tile
#define NJT 9     // ceil(513/64)
#define HSW 132   // hs row stride (floats) = 2*64+4
#define XSN 544   // xs floats

typedef float f32x4 __attribute__((ext_vector_type(4)));

// ---------------------------------------------------------------- kF ---------
// grid: 256 b x 9 jt. J0 = jt*64. h positions dp in [0,132), p = 2*J0-2+dp.
__global__ __launch_bounds__(256) void kF_front(const float* __restrict__ x,
                                                const float* __restrict__ w0,
                                                const float* __restrict__ b0,
                                                const float* __restrict__ bng,
                                                const float* __restrict__ bnb,
                                                const float* __restrict__ bnm,
                                                const float* __restrict__ bnv,
                                                const float* __restrict__ w1,
                                                const float* __restrict__ b1,
                                                unsigned short* __restrict__ m1,
                                                const float* __restrict__ w2,
                                                float* __restrict__ w2t2,
                                                unsigned* __restrict__ cnt_g,
                                                int* __restrict__ done_g) {
  __shared__ __align__(16) float xs[XSN];       //  2176 B  x window (+guard)
  __shared__ __align__(16) float hs[16 * HSW];  //  8448 B  h tile
  __shared__ __align__(16) float wl[2560];      // 10240 B  w1 transposed
  __shared__ float w0s[112];
  __shared__ float cpar[64];                    // per c: m, g, bb, bc
  __shared__ float rs_l[16];
  int bid = blockIdx.x;
  int b = bid / NJT, jt = bid % NJT;
  int J0 = jt * JT;
  int Pstart = 2 * J0 - 2;
  int tid = threadIdx.x;

  // ---- zero fused-head accumulators (consumed by kD after kernel boundary)
  {
    int g = bid * 256 + tid;
    if (g < 256 * 1024) cnt_g[g] = 0u;
    if (g < 256) done_g[g] = 0;
  }

  // ---- phase 1: stage x window + w1 transpose + conv0 constants
  if (tid < 16) rs_l[tid] = (float)(1.0 / sqrt((double)bnv[tid] + 1e-5));
  {
    const float* xb = x + (size_t)b * LX;
    int xoff = 4 * Pstart - 5;
    for (int i = tid; i < XSN; i += 256) {
      int gi = xoff + i;
      xs[i] = (gi >= 0 && gi < LX) ? xb[gi] : 0.f;
    }
    for (int i = tid; i < 2560; i += 256) {
      wl[i] = w1[(i & 31) * 80 + (i >> 5)];   // wl[(ic*5+k)*32 + c]
    }
    if (tid < 112) w0s[tid] = w0[tid];
    if (tid >= 128 && tid < 192) {
      int i = tid - 128;
      int c = i >> 2, e = i & 3;
      float v = (e == 0) ? bnm[c] : (e == 1) ? bng[c] : (e == 2) ? bnb[c] : b0[c];
      cpar[i] = v;
    }
  }
  __syncthreads();

  // ---- phase 2: conv0 + BN + ReLU + maxpool -> hs[c][dp], p = Pstart+dp
  {
    int c2 = tid >> 4, g2 = tid & 15;
    float m = cpar[4 * c2], g = cpar[4 * c2 + 1], bb = cpar[4 * c2 + 2],
          bc = cpar[4 * c2 + 3];
    float rs = rs_l[c2];
    float wv[7];
#pragma unroll
    for (int k = 0; k < 7; ++k) wv[k] = w0s[c2 * 7 + k];
    int dp0 = g2 * 9;
    const f32x4* xv = (const f32x4*)xs;
    f32x4 q0 = xv[dp0], q1 = xv[dp0 + 1], q2 = xv[dp0 + 2];
#pragma unroll
    for (int i = 0; i < 9; ++i) {
      int dp = dp0 + i;
      if (dp >= 132) break;
      int p = Pstart + dp;
      float hm = 0.f;
      if (p >= 0 && p < LP) {
        float win[12] = {q0.x, q0.y, q0.z, q0.w, q1.x, q1.y, q1.z, q1.w,
                         q2.x, q2.y, q2.z, q2.w};
        float best = -INFINITY;
#pragma unroll
        for (int dq = -1; dq <= 1; ++dq) {
          int q = 2 * p + dq;
          if (q < 0 || q >= LQ) continue;
          float s = 0.f;
          int base = 2 * dq + 2;
#pragma unroll
          for (int k = 0; k < 7; ++k) s = fmaf(win[base + k], wv[k], s);
          float y = s + bc;
          y = (y - m) * rs * g + bb;
          y = fmaxf(y, 0.f);
          best = fmaxf(best, y);
        }
        hm = best;
      }
      hs[c2 * HSW + dp] = hm;
      q0 = q1; q1 = q2; q2 = xv[dp + 3];   // max xv[134] -> floats <540 < XSN
    }
  }
  __syncthreads();

  // ---- phase 3: conv1 + 16-step LIF (const input) -> m1
  {
    int c = tid & 31, jg = tid >> 5;       // 8 groups x 8 j
    int jbase = J0 + jg * 8;
    if (jbase <= 512) {
      float acc[8];
#pragma unroll
      for (int i = 0; i < 8; ++i) acc[i] = 0.f;

#pragma unroll 1   // R16 lesson: full unroll of ic -> VGPR 148; body has 8-way ILP
      for (int ic = 0; ic < 16; ++ic) {
        float win[20];
        const f32x4* row = (const f32x4*)(hs + ic * HSW + 16 * jg);
#pragma unroll
        for (int i = 0; i < 5; ++i) {
          f32x4 v = row[i];
          win[4 * i] = v.x; win[4 * i + 1] = v.y;
          win[4 * i + 2] = v.z; win[4 * i + 3] = v.w;
        }
        float wv[5];
#pragma unroll
        for (int k = 0; k < 5; ++k) wv[k] = wl[(ic * 5 + k) * 32 + c];
#pragma unroll
        for (int j = 0; j < 8; ++j) {
#pragma unroll
          for (int k = 0; k < 5; ++k) acc[j] = fmaf(win[2 * j + k], wv[k], acc[j]);
        }
      }

      float bc = b1[c];
      unsigned mskv[8];
#pragma unroll
      for (int j = 0; j < 8; ++j) {
        float xin = acc[j] + bc;
        float v = 0.f; unsigned mm = 0;
#pragma unroll
        for (int t = 0; t < 16; ++t) {
          v = v + (xin - v) * 0.5f;
          if (v >= 1.f) { mm |= (1u << t); v = 0.f; }
        }
        mskv[j] = mm;
      }
      size_t rowo = ((size_t)b * 32 + c) * M1S + jbase;
      if (jbase + 7 < LJ1) {
        uint4 u0;                          // 8 u16 = 16B; rowo mult of 8 -> aligned
        u0.x = mskv[0] | (mskv[1] << 16);
        u0.y = mskv[2] | (mskv[3] << 16);
        u0.z = mskv[4] | (mskv[5] << 16);
        u0.w = mskv[6] | (mskv[7] << 16);
        *(uint4*)(m1 + rowo) = u0;
      } else {
        for (int j = 0; j < 8; ++j)
          if (jbase + j < LJ1) m1[rowo + j] = (unsigned short)mskv[j];
      }
    }
  }

  // ---- tail: w2 repack -> w2t2[c][oc][4] (blocks 0..15); kD waits on kF
  if (bid < 16) {
    for (int idx = bid * 256 + tid; idx < 64 * 32 * 3; idx += 4096) {
      int k = idx % 3; int r = idx / 3; int cc = r % 32; int oc = r / 32;
      w2t2[((size_t)cc * 64 + oc) * 4 + k] = w2[idx];
    }
  }
}

// ---------------------------------------------------------------- kD ---------
// grid: 256 b x 33 jt; block 4 waves; wave w -> j = jt*4+w; lane = oc.
// conv2+LIF2 (R18 core) + fused kE: atomic partial counts; last block runs head.
__global__ __launch_bounds__(256) void kD_conv2_lif(const unsigned short* __restrict__ m1,
                                                    const float* __restrict__ w2t2,
                                                    const float* __restrict__ b2,
                                                    unsigned* __restrict__ cnt_g,
                                                    int* __restrict__ done_g,
                                                    const float* __restrict__ fc1w,
                                                    const float* __restrict__ fc1b,
                                                    const float* __restrict__ fc2w,
                                                    const float* __restrict__ fc2b,
                                                    float* __restrict__ out) {
  __shared__ __align__(16) float F[288 * 20];     // 23040 B (head reuses as meanL)
  __shared__ unsigned mval[288];                  //  1152 B (reused as mmbuf)
  __shared__ unsigned s3m[32];
  __shared__ int lastflag;
  int bid = blockIdx.x;
  int b = bid / 33, jt = bid % 33;
  int j0 = jt * 4;
  int tid = threadIdx.x;
  int w = tid >> 6;      // wave id = j offset
  int lane = tid & 63;   // oc

  const unsigned short* m1b = m1 + (size_t)b * 32 * M1S;

  for (int it = tid; it < 288; it += 256) {
    int c = it / 9, idx = it - c * 9;
    int p = 2 * j0 - 1 + idx;
    unsigned m = 0;
    if (p >= 0 && p < LP1) {
      const unsigned short* mr = m1b + (size_t)c * M1S;
      int q0 = 2 * p - 1;
      if (q0 >= 0) m |= mr[q0];
      m |= mr[q0 + 1];                    // 2p in [0,512], always valid
      if (q0 + 2 <= 512) m |= mr[q0 + 2];
    }
    mval[it] = m;
    f32x4* Fr = (f32x4*)(F + it * 20);
    f32x4 f0, f1, f2, f3;
    f0.x = (float)(m & 1u);         f0.y = (float)((m >> 1) & 1u);
    f0.z = (float)((m >> 2) & 1u);  f0.w = (float)((m >> 3) & 1u);
    f1.x = (float)((m >> 4) & 1u);  f1.y = (float)((m >> 5) & 1u);
    f1.z = (float)((m >> 6) & 1u);  f1.w = (float)((m >> 7) & 1u);
    f2.x = (float)((m >> 8) & 1u);  f2.y = (float)((m >> 9) & 1u);
    f2.z = (float)((m >> 10) & 1u); f2.w = (float)((m >> 11) & 1u);
    f3.x = (float)((m >> 12) & 1u); f3.y = (float)((m >> 13) & 1u);
    f3.z = (float)((m >> 14) & 1u); f3.w = (float)((m >> 15) & 1u);
    Fr[0] = f0; Fr[1] = f1; Fr[2] = f2; Fr[3] = f3;
  }
  __syncthreads();

  // per-position presence masks in SGPRs
  bool nz0 = false, nz1 = false, nz2 = false;
  if (lane < 32) {
    int mb = lane * 9 + 2 * w;
    nz0 = mval[mb] != 0u;
    nz1 = mval[mb + 1] != 0u;
    nz2 = mval[mb + 2] != 0u;
  }
  unsigned bz0 = (unsigned)__ballot(nz0);
  unsigned bz1 = (unsigned)__ballot(nz1);
  unsigned bz2 = (unsigned)__ballot(nz2);
  unsigned bits = bz0 | bz1 | bz2;

  float acc[16];
#pragma unroll
  for (int t = 0; t < 16; ++t) acc[t] = 0.f;

  const f32x4* wbase = (const f32x4*)w2t2 + lane;  // + c*64 -> [c][oc][4]
  while (bits) {
    int c = __builtin_ctz(bits);
    bits &= bits - 1;
    int base9 = c * 9 + 2 * w;
    f32x4 wq = wbase[c * 64];          // one coalesced b128: w[k=0..2] (+pad)
    const float* Fb = F + base9 * 20;
    if ((bz0 >> c) & 1u) {
      const f32x4* Fp = (const f32x4*)Fb;
      f32x4 fv[4];
      fv[0] = Fp[0]; fv[1] = Fp[1]; fv[2] = Fp[2]; fv[3] = Fp[3];
#pragma unroll
      for (int t = 0; t < 16; ++t) acc[t] = fmaf(wq.x, fv[t >> 2][t & 3], acc[t]);
    }
    if ((bz1 >> c) & 1u) {
      const f32x4* Fp = (const f32x4*)(Fb + 20);
      f32x4 fv[4];
      fv[0] = Fp[0]; fv[1] = Fp[1]; fv[2] = Fp[2]; fv[3] = Fp[3];
#pragma unroll
      for (int t = 0; t < 16; ++t) acc[t] = fmaf(wq.y, fv[t >> 2][t & 3], acc[t]);
    }
    if ((bz2 >> c) & 1u) {
      const f32x4* Fp = (const f32x4*)(Fb + 40);
      f32x4 fv[4];
      fv[0] = Fp[0]; fv[1] = Fp[1]; fv[2] = Fp[2]; fv[3] = Fp[3];
#pragma unroll
      for (int t = 0; t < 16; ++t) acc[t] = fmaf(wq.z, fv[t >> 2][t & 3], acc[t]);
    }
  }

  // ---- LIF2 -> spike mask (zeroed for invalid j)
  unsigned mm_final = 0;
  {
    int j = j0 + w;
    float bc = b2[lane];
    float v = 0.f; unsigned mm = 0;
#pragma unroll
    for (int t = 0; t < 16; ++t) {
      float xin = acc[t] + bc;
      v = v + (xin - v) * 0.5f;
      if (v >= 1.f) { mm |= (1u << t); v = 0.f; }
    }
    mm_final = (j < LJ2) ? mm : 0u;
  }

  // ---- fused kE stage 1: partial popcounts -> device-scope atomics
  __syncthreads();                       // all F/mval reads done
  unsigned* mmbuf = mval;                // overlay [4][64]
  mmbuf[w * 64 + lane] = mm_final;
  __syncthreads();
#pragma unroll
  for (int i = 0; i < 4; ++i) {
    int idx = tid + 256 * i;             // idx = t*64 + oc
    unsigned p = 0;
#pragma unroll
    for (int ww = 0; ww < 4; ++ww) p += (mmbuf[ww * 64 + (idx & 63)] >> (idx >> 6)) & 1u;
    if (p) atomicAdd(&cnt_g[((size_t)b << 10) + idx], p);
  }
  __threadfence();
  if (tid == 0) {
    int old = __hip_atomic_fetch_add(&done_g[b], 1, __ATOMIC_ACQ_REL,
                                     __HIP_MEMORY_SCOPE_AGENT);
    lastflag = (old == 32) ? 1 : 0;
  }
  __syncthreads();

  // ---- fused kE stage 2 (head): only the last block per b
  if (lastflag) {
    __threadfence();
    float* meanL = F;                    // overlay [16][64]
#pragma unroll
    for (int i = 0; i < 4; ++i) {
      int idx = tid + 256 * i;
      unsigned cv = __hip_atomic_load(&cnt_g[((size_t)b << 10) + idx],
                                      __ATOMIC_RELAXED, __HIP_MEMORY_SCOPE_AGENT);
      meanL[idx] = (float)cv / 129.f;    // meanL[t*64 + oc]
    }
    __syncthreads();

    if (tid < 32) {
      int o = tid;
      const float* wrow = fc1w + o * 64;
      float bb = fc1b[o];
      float v = 0.f;
      unsigned msk = 0;
      for (int t = 0; t < 16; ++t) {
        float s = 0.f;
        for (int d = 0; d < 64; ++d) s = fmaf(meanL[t * 64 + d], wrow[d], s);
        float xin = s + bb;
        v = v + (xin - v) * 0.5f;
        if (v >= 1.f) { msk |= (1u << t); v = 0.f; }
      }
      s3m[o] = msk;
    }
    __syncthreads();

    if (tid < 5) {
      int q = tid;
      const float* wrow = fc2w + q * 32;
      float bb = fc2b[q];
      float accs = 0.f;
      for (int t = 0; t < 16; ++t) {
        float s = 0.f;
        for (int o = 0; o < 32; ++o) s += (((s3m[o] >> t) & 1u) ? wrow[o] : 0.f);
        accs += (s + bb);
      }
      out[b * 5 + q] = accs / 16.f;
    }
  }
}

extern "C" void kernel_launch(void* const* d_in, const int* in_sizes, int n_in,
                              void* d_out, int out_size, void* d_ws, size_t ws_size,
                              hipStream_t stream) {
  const float* x   = (const float*)d_in[0];
  const float* w0  = (const float*)d_in[1];
  const float* b0  = (const float*)d_in[2];
  const float* bng = (const float*)d_in[3];
  const float* bnb = (const float*)d_in[4];
  const float* bnm = (const float*)d_in[5];
  const float* bnv = (const float*)d_in[6];
  const float* w1  = (const float*)d_in[7];
  const float* b1  = (const float*)d_in[8];
  const float* w2  = (const float*)d_in[9];
  const float* b2  = (const float*)d_in[10];
  const float* f1w = (const float*)d_in[11];
  const float* f1b = (const float*)d_in[12];
  const float* f2w = (const float*)d_in[13];
  const float* f2b = (const float*)d_in[14];
  float* out = (float*)d_out;

  char* ws = (char*)d_ws;
  size_t sz_m1  = (size_t)NB * 32 * M1S * 2;     // 8,519,680
  size_t off_w2 = sz_m1;
  size_t off_cn = off_w2 + 32768;
  size_t off_dn = off_cn + (size_t)256 * 1024 * 4;   // cnt_g 1MB
  if (ws_size < off_dn + 1024) return;           // ~9.6 MB needed

  unsigned short* m1 = (unsigned short*)ws;
  float* w2t2 = (float*)(ws + off_w2);
  unsigned* cnt_g = (unsigned*)(ws + off_cn);
  int* done_g = (int*)(ws + off_dn);

  kF_front<<<NB * NJT, 256, 0, stream>>>(x, w0, b0, bng, bnb, bnm, bnv, w1, b1,
                                         m1, w2, w2t2, cnt_g, done_g);
  kD_conv2_lif<<<NB * 33, 256, 0, stream>>>(m1, w2t2, b2, cnt_g, done_g,
                                            f1w, f1b, f2w, f2b, out);
}

// Round 21
// 106.029 us; speedup vs baseline: 7.9585x; 7.9585x over previous
//
#include <hip/hip_runtime.h>
#include <math.h>

// HybridSNN: time-collapsed spiking CNN (exact fp32 replication, bit-exact orders).
// R21 = revert to R18 config (106.2us, session best). R19 pipelining: neutral.
// R20 atomic-fused kE: 8.6M device-scope atomics serialized -> 820us kD. Dead end.
//  kF: conv0+BN+ReLU+maxpool (h tile in LDS) + conv1 + serial LIF1 -> m1.
//      JT=64, unroll-1 pin, w1->LDS wl, w2 repack tail.
//  kD: maxpool(OR) + conv2 over bits + LIF2 -> s2 [256][132][64] u16.
//      F-build reads m1 direct from L2; per-c guards in SGPR ballot masks.
//  kE: popcount-mean + fc1 + LIF3 + fc2 -> out [256][5] f32.

#define NB 256
#define LX 4097
#define LQ 2049
#define LP 1025
#define LJ1 513
#define LP1 257
#define LJ2 129

#define M1S 520
#define S2R 132
#define JT 64     // kF j-tile
#define NJT 9     // ceil(513/64)
#define HSW 132   // hs row stride (floats) = 2*64+4
#define XSN 544   // xs floats

typedef float f32x4 __attribute__((ext_vector_type(4)));

// ---------------------------------------------------------------- kF ---------
// grid: 256 b x 9 jt. J0 = jt*64. h positions dp in [0,132), p = 2*J0-2+dp.
__global__ __launch_bounds__(256) void kF_front(const float* __restrict__ x,
                                                const float* __restrict__ w0,
                                                const float* __restrict__ b0,
                                                const float* __restrict__ bng,
                                                const float* __restrict__ bnb,
                                                const float* __restrict__ bnm,
                                                const float* __restrict__ bnv,
                                                const float* __restrict__ w1,
                                                const float* __restrict__ b1,
                                                unsigned short* __restrict__ m1,
                                                const float* __restrict__ w2,
                                                float* __restrict__ w2t2) {
  __shared__ __align__(16) float xs[XSN];       //  2176 B  x window (+guard)
  __shared__ __align__(16) float hs[16 * HSW];  //  8448 B  h tile
  __shared__ __align__(16) float wl[2560];      // 10240 B  w1 transposed
  __shared__ float w0s[112];
  __shared__ float cpar[64];                    // per c: m, g, bb, bc
  __shared__ float rs_l[16];
  int bid = blockIdx.x;
  int b = bid / NJT, jt = bid % NJT;
  int J0 = jt * JT;
  int Pstart = 2 * J0 - 2;
  int tid = threadIdx.x;

  // ---- phase 1: stage x window + w1 transpose + conv0 constants
  if (tid < 16) rs_l[tid] = (float)(1.0 / sqrt((double)bnv[tid] + 1e-5));
  {
    const float* xb = x + (size_t)b * LX;
    int xoff = 4 * Pstart - 5;
    for (int i = tid; i < XSN; i += 256) {
      int gi = xoff + i;
      xs[i] = (gi >= 0 && gi < LX) ? xb[gi] : 0.f;
    }
    for (int i = tid; i < 2560; i += 256) {
      wl[i] = w1[(i & 31) * 80 + (i >> 5)];   // wl[(ic*5+k)*32 + c]
    }
    if (tid < 112) w0s[tid] = w0[tid];
    if (tid >= 128 && tid < 192) {
      int i = tid - 128;
      int c = i >> 2, e = i & 3;
      float v = (e == 0) ? bnm[c] : (e == 1) ? bng[c] : (e == 2) ? bnb[c] : b0[c];
      cpar[i] = v;
    }
  }
  __syncthreads();

  // ---- phase 2: conv0 + BN + ReLU + maxpool -> hs[c][dp], p = Pstart+dp
  {
    int c2 = tid >> 4, g2 = tid & 15;
    float m = cpar[4 * c2], g = cpar[4 * c2 + 1], bb = cpar[4 * c2 + 2],
          bc = cpar[4 * c2 + 3];
    float rs = rs_l[c2];
    float wv[7];
#pragma unroll
    for (int k = 0; k < 7; ++k) wv[k] = w0s[c2 * 7 + k];
    int dp0 = g2 * 9;
    const f32x4* xv = (const f32x4*)xs;
    f32x4 q0 = xv[dp0], q1 = xv[dp0 + 1], q2 = xv[dp0 + 2];
#pragma unroll
    for (int i = 0; i < 9; ++i) {
      int dp = dp0 + i;
      if (dp >= 132) break;
      int p = Pstart + dp;
      float hm = 0.f;
      if (p >= 0 && p < LP) {
        float win[12] = {q0.x, q0.y, q0.z, q0.w, q1.x, q1.y, q1.z, q1.w,
                         q2.x, q2.y, q2.z, q2.w};
        float best = -INFINITY;
#pragma unroll
        for (int dq = -1; dq <= 1; ++dq) {
          int q = 2 * p + dq;
          if (q < 0 || q >= LQ) continue;
          float s = 0.f;
          int base = 2 * dq + 2;
#pragma unroll
          for (int k = 0; k < 7; ++k) s = fmaf(win[base + k], wv[k], s);
          float y = s + bc;
          y = (y - m) * rs * g + bb;
          y = fmaxf(y, 0.f);
          best = fmaxf(best, y);
        }
        hm = best;
      }
      hs[c2 * HSW + dp] = hm;
      q0 = q1; q1 = q2; q2 = xv[dp + 3];   // max xv[134] -> floats <540 < XSN
    }
  }
  __syncthreads();

  // ---- phase 3: conv1 + 16-step LIF (const input) -> m1
  {
    int c = tid & 31, jg = tid >> 5;       // 8 groups x 8 j
    int jbase = J0 + jg * 8;
    if (jbase <= 512) {
      float acc[8];
#pragma unroll
      for (int i = 0; i < 8; ++i) acc[i] = 0.f;

#pragma unroll 1   // R16 lesson: full unroll of ic -> VGPR 148; body has 8-way ILP
      for (int ic = 0; ic < 16; ++ic) {
        float win[20];
        const f32x4* row = (const f32x4*)(hs + ic * HSW + 16 * jg);
#pragma unroll
        for (int i = 0; i < 5; ++i) {
          f32x4 v = row[i];
          win[4 * i] = v.x; win[4 * i + 1] = v.y;
          win[4 * i + 2] = v.z; win[4 * i + 3] = v.w;
        }
        float wv[5];
#pragma unroll
        for (int k = 0; k < 5; ++k) wv[k] = wl[(ic * 5 + k) * 32 + c];
#pragma unroll
        for (int j = 0; j < 8; ++j) {
#pragma unroll
          for (int k = 0; k < 5; ++k) acc[j] = fmaf(win[2 * j + k], wv[k], acc[j]);
        }
      }

      float bc = b1[c];
      unsigned mskv[8];
#pragma unroll
      for (int j = 0; j < 8; ++j) {
        float xin = acc[j] + bc;
        float v = 0.f; unsigned mm = 0;
#pragma unroll
        for (int t = 0; t < 16; ++t) {
          v = v + (xin - v) * 0.5f;
          if (v >= 1.f) { mm |= (1u << t); v = 0.f; }
        }
        mskv[j] = mm;
      }
      size_t rowo = ((size_t)b * 32 + c) * M1S + jbase;
      if (jbase + 7 < LJ1) {
        uint4 u0;                          // 8 u16 = 16B; rowo mult of 8 -> aligned
        u0.x = mskv[0] | (mskv[1] << 16);
        u0.y = mskv[2] | (mskv[3] << 16);
        u0.z = mskv[4] | (mskv[5] << 16);
        u0.w = mskv[6] | (mskv[7] << 16);
        *(uint4*)(m1 + rowo) = u0;
      } else {
        for (int j = 0; j < 8; ++j)
          if (jbase + j < LJ1) m1[rowo + j] = (unsigned short)mskv[j];
      }
    }
  }

  // ---- tail: w2 repack -> w2t2[c][oc][4] (blocks 0..15); kD waits on kF
  if (bid < 16) {
    for (int idx = bid * 256 + tid; idx < 64 * 32 * 3; idx += 4096) {
      int k = idx % 3; int r = idx / 3; int cc = r % 32; int oc = r / 32;
      w2t2[((size_t)cc * 64 + oc) * 4 + k] = w2[idx];
    }
  }
}

// ---------------------------------------------------------------- kD ---------
// grid: 256 b x 33 jt; block 4 waves; wave w -> j = jt*4+w; lane = oc.
// F-build reads m1 direct from L2; per-c guards in SGPR ballot masks.
__global__ __launch_bounds__(256) void kD_conv2_lif(const unsigned short* __restrict__ m1,
                                                    const float* __restrict__ w2t2,
                                                    const float* __restrict__ b2,
                                                    unsigned short* __restrict__ s2) {
  __shared__ __align__(16) float F[288 * 20];     // 23040 B, 80B rows (conflict-free)
  __shared__ unsigned mval[288];                  //  1152 B
  int bid = blockIdx.x;
  int b = bid / 33, jt = bid % 33;
  int j0 = jt * 4;
  int tid = threadIdx.x;
  int w = tid >> 6;      // wave id = j offset
  int lane = tid & 63;   // oc

  const unsigned short* m1b = m1 + (size_t)b * 32 * M1S;

  for (int it = tid; it < 288; it += 256) {
    int c = it / 9, idx = it - c * 9;
    int p = 2 * j0 - 1 + idx;
    unsigned m = 0;
    if (p >= 0 && p < LP1) {
      const unsigned short* mr = m1b + (size_t)c * M1S;
      int q0 = 2 * p - 1;
      if (q0 >= 0) m |= mr[q0];
      m |= mr[q0 + 1];                    // 2p in [0,512], always valid
      if (q0 + 2 <= 512) m |= mr[q0 + 2];
    }
    mval[it] = m;
    f32x4* Fr = (f32x4*)(F + it * 20);
    f32x4 f0, f1, f2, f3;
    f0.x = (float)(m & 1u);         f0.y = (float)((m >> 1) & 1u);
    f0.z = (float)((m >> 2) & 1u);  f0.w = (float)((m >> 3) & 1u);
    f1.x = (float)((m >> 4) & 1u);  f1.y = (float)((m >> 5) & 1u);
    f1.z = (float)((m >> 6) & 1u);  f1.w = (float)((m >> 7) & 1u);
    f2.x = (float)((m >> 8) & 1u);  f2.y = (float)((m >> 9) & 1u);
    f2.z = (float)((m >> 10) & 1u); f2.w = (float)((m >> 11) & 1u);
    f3.x = (float)((m >> 12) & 1u); f3.y = (float)((m >> 13) & 1u);
    f3.z = (float)((m >> 14) & 1u); f3.w = (float)((m >> 15) & 1u);
    Fr[0] = f0; Fr[1] = f1; Fr[2] = f2; Fr[3] = f3;
  }
  __syncthreads();

  // per-position presence masks in SGPRs (one LDS read burst, then scalar tests)
  bool nz0 = false, nz1 = false, nz2 = false;
  if (lane < 32) {
    int mb = lane * 9 + 2 * w;
    nz0 = mval[mb] != 0u;
    nz1 = mval[mb + 1] != 0u;
    nz2 = mval[mb + 2] != 0u;
  }
  unsigned bz0 = (unsigned)__ballot(nz0);
  unsigned bz1 = (unsigned)__ballot(nz1);
  unsigned bz2 = (unsigned)__ballot(nz2);
  unsigned bits = bz0 | bz1 | bz2;

  float acc[16];
#pragma unroll
  for (int t = 0; t < 16; ++t) acc[t] = 0.f;

  const f32x4* wbase = (const f32x4*)w2t2 + lane;  // + c*64 -> [c][oc][4]
  while (bits) {
    int c = __builtin_ctz(bits);
    bits &= bits - 1;
    int base9 = c * 9 + 2 * w;
    f32x4 wq = wbase[c * 64];          // one coalesced b128: w[k=0..2] (+pad)
    const float* Fb = F + base9 * 20;
    if ((bz0 >> c) & 1u) {
      const f32x4* Fp = (const f32x4*)Fb;
      f32x4 fv[4];
      fv[0] = Fp[0]; fv[1] = Fp[1]; fv[2] = Fp[2]; fv[3] = Fp[3];
#pragma unroll
      for (int t = 0; t < 16; ++t) acc[t] = fmaf(wq.x, fv[t >> 2][t & 3], acc[t]);
    }
    if ((bz1 >> c) & 1u) {
      const f32x4* Fp = (const f32x4*)(Fb + 20);
      f32x4 fv[4];
      fv[0] = Fp[0]; fv[1] = Fp[1]; fv[2] = Fp[2]; fv[3] = Fp[3];
#pragma unroll
      for (int t = 0; t < 16; ++t) acc[t] = fmaf(wq.y, fv[t >> 2][t & 3], acc[t]);
    }
    if ((bz2 >> c) & 1u) {
      const f32x4* Fp = (const f32x4*)(Fb + 40);
      f32x4 fv[4];
      fv[0] = Fp[0]; fv[1] = Fp[1]; fv[2] = Fp[2]; fv[3] = Fp[3];
#pragma unroll
      for (int t = 0; t < 16; ++t) acc[t] = fmaf(wq.z, fv[t >> 2][t & 3], acc[t]);
    }
  }

  int j = j0 + w;
  if (j < LJ2) {
    float bc = b2[lane];
    float v = 0.f; unsigned mm = 0;
#pragma unroll
    for (int t = 0; t < 16; ++t) {
      float xin = acc[t] + bc;
      v = v + (xin - v) * 0.5f;
      if (v >= 1.f) { mm |= (1u << t); v = 0.f; }
    }
    s2[((size_t)b * S2R + j) * 64 + lane] = (unsigned short)mm;  // coalesced
  }
}

// ---------------------------------------------------------------- kE ---------
// block = 256 thr per b; wave = j chunk, lane = oc (coalesced 128B rows)
__global__ __launch_bounds__(256) void kE_head(const unsigned short* __restrict__ s2,
                                               const float* __restrict__ fc1w,
                                               const float* __restrict__ fc1b,
                                               const float* __restrict__ fc2w,
                                               const float* __restrict__ fc2b,
                                               float* __restrict__ out) {
  __shared__ unsigned cntL[4][16][64];   // 16 KB
  __shared__ float meanL[16][64];        //  4 KB
  __shared__ unsigned s3m[32];
  int b = blockIdx.x;
  int tid = threadIdx.x;
  int w = tid >> 6, lane = tid & 63;

  int j0 = (w == 0) ? 0 : 33 + 32 * (w - 1);
  int jc = (w == 0) ? 33 : 32;
  const unsigned short* base = s2 + (size_t)b * S2R * 64 + lane;
  unsigned cnt[16];
#pragma unroll
  for (int t = 0; t < 16; ++t) cnt[t] = 0;
  for (int u = 0; u < jc; ++u) {
    unsigned m = base[(size_t)(j0 + u) * 64];
#pragma unroll
    for (int t = 0; t < 16; ++t) cnt[t] += (m >> t) & 1u;
  }
#pragma unroll
  for (int t = 0; t < 16; ++t) cntL[w][t][lane] = cnt[t];
  __syncthreads();

#pragma unroll
  for (int i = 0; i < 4; ++i) {
    int idx = tid + 256 * i;
    int t = idx >> 6, oc = idx & 63;
    unsigned s = cntL[0][t][oc] + cntL[1][t][oc] + cntL[2][t][oc] + cntL[3][t][oc];
    meanL[t][oc] = (float)s / 129.f;
  }
  __syncthreads();

  if (tid < 32) {
    int o = tid;
    const float* wrow = fc1w + o * 64;
    float bb = fc1b[o];
    float v = 0.f;
    unsigned msk = 0;
    for (int t = 0; t < 16; ++t) {
      float s = 0.f;
      for (int d = 0; d < 64; ++d) s = fmaf(meanL[t][d], wrow[d], s);
      float xin = s + bb;
      v = v + (xin - v) * 0.5f;
      if (v >= 1.f) { msk |= (1u << t); v = 0.f; }
    }
    s3m[o] = msk;
  }
  __syncthreads();

  if (tid < 5) {
    int q = tid;
    const float* wrow = fc2w + q * 32;
    float bb = fc2b[q];
    float accs = 0.f;
    for (int t = 0; t < 16; ++t) {
      float s = 0.f;
      for (int o = 0; o < 32; ++o) s += (((s3m[o] >> t) & 1u) ? wrow[o] : 0.f);
      accs += (s + bb);
    }
    out[b * 5 + q] = accs / 16.f;
  }
}

extern "C" void kernel_launch(void* const* d_in, const int* in_sizes, int n_in,
                              void* d_out, int out_size, void* d_ws, size_t ws_size,
                              hipStream_t stream) {
  const float* x   = (const float*)d_in[0];
  const float* w0  = (const float*)d_in[1];
  const float* b0  = (const float*)d_in[2];
  const float* bng = (const float*)d_in[3];
  const float* bnb = (const float*)d_in[4];
  const float* bnm = (const float*)d_in[5];
  const float* bnv = (const float*)d_in[6];
  const float* w1  = (const float*)d_in[7];
  const float* b1  = (const float*)d_in[8];
  const float* w2  = (const float*)d_in[9];
  const float* b2  = (const float*)d_in[10];
  const float* f1w = (const float*)d_in[11];
  const float* f1b = (const float*)d_in[12];
  const float* f2w = (const float*)d_in[13];
  const float* f2b = (const float*)d_in[14];
  float* out = (float*)d_out;

  char* ws = (char*)d_ws;
  size_t sz_m1 = (size_t)NB * 32 * M1S * 2;      // 8,519,680
  size_t sz_s2 = (size_t)NB * S2R * 64 * 2;      // 4,325,376
  size_t off_s2 = sz_m1;
  size_t off_w2 = off_s2 + sz_s2;
  if (ws_size < off_w2 + 32768) return;          // ~12.9 MB needed

  unsigned short* m1 = (unsigned short*)ws;
  unsigned short* s2 = (unsigned short*)(ws + off_s2);
  float* w2t2 = (float*)(ws + off_w2);

  kF_front<<<NB * NJT, 256, 0, stream>>>(x, w0, b0, bng, bnb, bnm, bnv, w1, b1, m1, w2, w2t2);
  kD_conv2_lif<<<NB * 33, 256, 0, stream>>>(m1, w2t2, b2, s2);
  kE_head<<<NB, 256, 0, stream>>>(s2, f1w, f1b, f2w, f2b, out);
}